// Round 7
// baseline (295.949 us; speedup 1.0000x reference)
//
#include <hip/hip_runtime.h>

#define LATENT 128
#define HEAD 8
#define DH 16

#define SCAN_BLOCK 2048    // elements scanned per block
#define SCAN_THREADS 256   // 8 elements per thread

typedef __attribute__((ext_vector_type(8))) short short8;
typedef __attribute__((ext_vector_type(4))) float floatx4;

__device__ inline float bf2f(unsigned short u) {
    return __uint_as_float(((unsigned int)u) << 16);
}
__device__ inline unsigned short f2bf(float f) {
    unsigned int b = __float_as_uint(f);
    b += 0x7fffu + ((b >> 16) & 1u);          // RNE
    return (unsigned short)(b >> 16);
}

// ---------------------------------------------------------------------------
// emb -> bf16 hi/lo split (precomputed so GEMM staging is pure copies)
// ---------------------------------------------------------------------------
__global__ __launch_bounds__(256) void convert_emb_hl(
    const float* __restrict__ in, unsigned short* __restrict__ hi,
    unsigned short* __restrict__ lo, int n4)
{
    int i = blockIdx.x * 256 + threadIdx.x;
    if (i >= n4) return;
    float4 v = ((const float4*)in)[i];
    ushort4 h, l;
    h.x = f2bf(v.x); l.x = f2bf(v.x - bf2f(h.x));
    h.y = f2bf(v.y); l.y = f2bf(v.y - bf2f(h.y));
    h.z = f2bf(v.z); l.z = f2bf(v.z - bf2f(h.z));
    h.w = f2bf(v.w); l.w = f2bf(v.w - bf2f(h.w));
    ((ushort4*)hi)[i] = h;
    ((ushort4*)lo)[i] = l;
}

// ---------------------------------------------------------------------------
// Split W into bf16 hi/lo, transposed: Wt{hi,lo}[mat][c][k] from W[mat][k][c]
// ---------------------------------------------------------------------------
__global__ __launch_bounds__(256) void convert_wt(
    const float* __restrict__ Wq, const float* __restrict__ Wk, const float* __restrict__ Wv,
    unsigned short* __restrict__ Wthi, unsigned short* __restrict__ Wtlo)
{
    int idx = blockIdx.x * 256 + threadIdx.x;
    if (idx >= 3 * LATENT * LATENT) return;
    int mat = idx >> 14;
    int r   = idx & 16383;
    int c   = r >> 7;
    int k   = r & 127;
    const float* W = (mat == 0) ? Wq : ((mat == 1) ? Wk : Wv);
    float x = W[k * LATENT + c];
    unsigned short hi = f2bf(x);
    Wthi[idx] = hi;
    Wtlo[idx] = f2bf(x - bf2f(hi));
}

// ---------------------------------------------------------------------------
// Kernel 1: QKV projection via split-bf16 MFMA.
// Q,K: 3-term (fp32-accurate); V: 1-term (bf16-accurate, linear in output).
// 128x128 tile, K=128 in 4 steps of 32. LDS XOR-swizzled (16B-chunk ^ (row&7)).
// Output: Q fp32, K bf16, V fp32.
// ---------------------------------------------------------------------------
__global__ __launch_bounds__(256) void qkv_gemm_mfma(
    const unsigned short* __restrict__ ehi, const unsigned short* __restrict__ elo,
    const unsigned short* __restrict__ Wthi, const unsigned short* __restrict__ Wtlo,
    float* __restrict__ Qf, unsigned short* __restrict__ Kb,
    float* __restrict__ Vf, int nNodes)
{
    __shared__ unsigned short sAhi[128 * 128];
    __shared__ unsigned short sAlo[128 * 128];
    __shared__ unsigned short sBhi[128 * 128];
    __shared__ unsigned short sBlo[128 * 128];   // 4 x 32 KB = 128 KB

    const int mat  = blockIdx.y;
    const int row0 = blockIdx.x * 128;
    const int tid  = threadIdx.x;
    const unsigned short* wthi = Wthi + mat * LATENT * LATENT;
    const unsigned short* wtlo = Wtlo + mat * LATENT * LATENT;

    // stage A (pre-split emb): 2048 16B-chunks each
#pragma unroll
    for (int it = 0; it < 8; ++it) {
        int g = it * 256 + tid;
        int r = g >> 4, c16 = g & 15;
        int gr = row0 + r;
        uint4 vh = make_uint4(0u, 0u, 0u, 0u);
        uint4 vl = make_uint4(0u, 0u, 0u, 0u);
        if (gr < nNodes) {
            vh = ((const uint4*)(ehi + (size_t)gr * LATENT))[c16];
            vl = ((const uint4*)(elo + (size_t)gr * LATENT))[c16];
        }
        int dst = r * 16 + (c16 ^ (r & 7));
        ((uint4*)sAhi)[dst] = vh;
        ((uint4*)sAlo)[dst] = vl;
    }
    // stage B: 2048 16B-chunks (lo only needed for Q,K)
#pragma unroll
    for (int it = 0; it < 8; ++it) {
        int g = it * 256 + tid;
        int r = g >> 4, c16 = g & 15;
        int dst = r * 16 + (c16 ^ (r & 7));
        ((uint4*)sBhi)[dst] = ((const uint4*)wthi)[g];
        if (mat < 2) ((uint4*)sBlo)[dst] = ((const uint4*)wtlo)[g];
    }
    __syncthreads();

    const int wid  = tid >> 6;
    const int lane = tid & 63;
    const int lrow = lane & 15;
    const int kgrp = lane >> 4;

    floatx4 acc[2][8];
#pragma unroll
    for (int rb = 0; rb < 2; ++rb)
#pragma unroll
        for (int cb = 0; cb < 8; ++cb)
            acc[rb][cb] = (floatx4){0.f, 0.f, 0.f, 0.f};

#pragma unroll
    for (int kk = 0; kk < 4; ++kk) {
        const int chunk = kk * 4 + kgrp;
        short8 ahi[2], alo[2], bhi[8], blo[8];
#pragma unroll
        for (int rb = 0; rb < 2; ++rb) {
            int rl  = wid * 32 + rb * 16 + lrow;
            int src = rl * 16 + (chunk ^ (rl & 7));
            ahi[rb] = ((const short8*)sAhi)[src];
            alo[rb] = ((const short8*)sAlo)[src];
        }
#pragma unroll
        for (int cb = 0; cb < 8; ++cb) {
            int cl  = cb * 16 + lrow;
            int src = cl * 16 + (chunk ^ (cl & 7));
            bhi[cb] = ((const short8*)sBhi)[src];
            blo[cb] = ((const short8*)sBlo)[src];
        }
        if (mat < 2) {
#pragma unroll
            for (int rb = 0; rb < 2; ++rb)
#pragma unroll
                for (int cb = 0; cb < 8; ++cb) {
                    acc[rb][cb] = __builtin_amdgcn_mfma_f32_16x16x32_bf16(
                        ahi[rb], bhi[cb], acc[rb][cb], 0, 0, 0);
                    acc[rb][cb] = __builtin_amdgcn_mfma_f32_16x16x32_bf16(
                        ahi[rb], blo[cb], acc[rb][cb], 0, 0, 0);
                    acc[rb][cb] = __builtin_amdgcn_mfma_f32_16x16x32_bf16(
                        alo[rb], bhi[cb], acc[rb][cb], 0, 0, 0);
                }
        } else {
#pragma unroll
            for (int rb = 0; rb < 2; ++rb)
#pragma unroll
                for (int cb = 0; cb < 8; ++cb)
                    acc[rb][cb] = __builtin_amdgcn_mfma_f32_16x16x32_bf16(
                        ahi[rb], bhi[cb], acc[rb][cb], 0, 0, 0);
        }
    }

    // C/D layout: col = lane&15, row = (lane>>4)*4 + reg   [m89-verified]
#pragma unroll
    for (int rb = 0; rb < 2; ++rb)
#pragma unroll
        for (int cb = 0; cb < 8; ++cb)
#pragma unroll
            for (int i = 0; i < 4; ++i) {
                int row = row0 + wid * 32 + rb * 16 + kgrp * 4 + i;
                int col = cb * 16 + lrow;
                if (row < nNodes) {
                    float v = acc[rb][cb][i];
                    if (mat == 0)      Qf[(size_t)row * LATENT + col] = v;
                    else if (mat == 1) Kb[(size_t)row * LATENT + col] = f2bf(v);
                    else               Vf[(size_t)row * LATENT + col] = v;
                }
            }
}

// ---------------------------------------------------------------------------
// CSR build: histogram -> exclusive scan (3 kernels) -> scatter
// ---------------------------------------------------------------------------
__global__ __launch_bounds__(256) void count_deg(
    const int* __restrict__ rows, int* __restrict__ deg, int nE)
{
    int e = blockIdx.x * 256 + threadIdx.x;
    if (e < nE) atomicAdd(&deg[rows[e]], 1);
}

__global__ __launch_bounds__(SCAN_THREADS) void scan_block(
    const int* __restrict__ deg, int* __restrict__ excl,
    int* __restrict__ blockSums, int n)
{
    __shared__ int sSum[SCAN_THREADS];
    int tid  = threadIdx.x;
    int base = blockIdx.x * SCAN_BLOCK + tid * 8;
    int v[8];
    int tot = 0;
#pragma unroll
    for (int i = 0; i < 8; ++i) {
        int idx = base + i;
        v[i] = (idx < n) ? deg[idx] : 0;
        tot += v[i];
    }
    sSum[tid] = tot;
    __syncthreads();
    for (int off = 1; off < SCAN_THREADS; off <<= 1) {
        int x = (tid >= off) ? sSum[tid - off] : 0;
        __syncthreads();
        sSum[tid] += x;
        __syncthreads();
    }
    int run = (tid > 0) ? sSum[tid - 1] : 0;
#pragma unroll
    for (int i = 0; i < 8; ++i) {
        int idx = base + i;
        if (idx < n) excl[idx] = run;
        run += v[i];
    }
    if (tid == SCAN_THREADS - 1) blockSums[blockIdx.x] = sSum[SCAN_THREADS - 1];
}

__global__ void scan_top(int* __restrict__ blockSums, int nb)
{
    if (threadIdx.x == 0) {
        int run = 0;
        for (int i = 0; i < nb; ++i) {
            int x = blockSums[i];
            blockSums[i] = run;
            run += x;
        }
    }
}

__global__ __launch_bounds__(256) void scan_add(
    const int* __restrict__ excl, const int* __restrict__ blockSums,
    int* __restrict__ start, int* __restrict__ cursor, int n)
{
    int i = blockIdx.x * 256 + threadIdx.x;
    if (i < n) {
        int s = excl[i] + blockSums[i / SCAN_BLOCK];
        start[i]  = s;
        cursor[i] = s;
    }
}

__global__ __launch_bounds__(256) void scatter_edges(
    const int* __restrict__ rows, int* __restrict__ cursor,
    int* __restrict__ edgeIdx, int nE)
{
    int e = blockIdx.x * 256 + threadIdx.x;
    if (e < nE) {
        int p = atomicAdd(&cursor[rows[e]], 1);
        edgeIdx[p] = e;
    }
}

// ---------------------------------------------------------------------------
// Kernel 2: fused node-centric scores + aggregate.
// ONE 64-lane wave per node: lanes 0-31 process edges [0,cnt/2), lanes 32-63
// process [cnt/2,cnt); within a half, lane t owns dims 4t..4t+3 (4 lanes/head).
// Halves combined via __shfl_xor(...,32). Unroll-4 -> 8 gather chains in
// flight per node. Q fp32 in registers; gathers K bf16 + V fp32.
// ---------------------------------------------------------------------------
__global__ __launch_bounds__(256) void node_fused(
    const float* __restrict__ Qf, const unsigned short* __restrict__ Kb,
    const float* __restrict__ Vf,
    const int* __restrict__ cols,
    const int* __restrict__ start, const int* __restrict__ deg,
    const int* __restrict__ edgeIdx,
    float* __restrict__ attOut,         // [E,8] <- exp (pre-normalization)
    float* __restrict__ rnArr,          // [N,8]
    float* __restrict__ outEmb, int nNodes)
{
    int node = blockIdx.x * 4 + (threadIdx.x >> 6);
    int lane = threadIdx.x & 63;
    int half = lane >> 5;
    int t    = lane & 31;               // lane owns dims 4t..4t+3
    if (node >= nNodes) return;
    int h = t >> 2;

    float4 q = ((const float4*)(Qf + (size_t)node * LATENT))[t];

    int s    = start[node];
    int cnt  = deg[node];
    int cnt2 = cnt >> 1;
    int jBeg = half ? cnt2 : 0;
    int jEnd = half ? cnt : cnt2;

    float4 acc = make_float4(0.f, 0.f, 0.f, 0.f);
    float norm = 0.f;

#define EDGE_BODY(E_, KU_, VV_)                                                \
    {                                                                          \
        float p = q.x * bf2f(KU_.x) + q.y * bf2f(KU_.y) +                      \
                  q.z * bf2f(KU_.z) + q.w * bf2f(KU_.w);                       \
        p += __shfl_xor(p, 1);                                                 \
        p += __shfl_xor(p, 2);                                                 \
        p = fminf(fmaxf(p, -10.f), 10.f);                                      \
        float ex = expf(p);                                                    \
        if ((t & 3) == 0) attOut[(size_t)E_ * HEAD + h] = ex;                  \
        norm += ex;                                                            \
        acc.x += ex * VV_.x; acc.y += ex * VV_.y;                              \
        acc.z += ex * VV_.z; acc.w += ex * VV_.w;                              \
    }

    int j = jBeg;
    for (; j + 4 <= jEnd; j += 4) {
        int e0 = edgeIdx[s + j + 0];
        int e1 = edgeIdx[s + j + 1];
        int e2 = edgeIdx[s + j + 2];
        int e3 = edgeIdx[s + j + 3];
        int c0 = cols[e0], c1 = cols[e1], c2 = cols[e2], c3 = cols[e3];
        ushort4 k0 = ((const ushort4*)(Kb + (size_t)c0 * LATENT))[t];
        ushort4 k1 = ((const ushort4*)(Kb + (size_t)c1 * LATENT))[t];
        ushort4 k2 = ((const ushort4*)(Kb + (size_t)c2 * LATENT))[t];
        ushort4 k3 = ((const ushort4*)(Kb + (size_t)c3 * LATENT))[t];
        float4 v0 = ((const float4*)(Vf + (size_t)c0 * LATENT))[t];
        float4 v1 = ((const float4*)(Vf + (size_t)c1 * LATENT))[t];
        float4 v2 = ((const float4*)(Vf + (size_t)c2 * LATENT))[t];
        float4 v3 = ((const float4*)(Vf + (size_t)c3 * LATENT))[t];
        EDGE_BODY(e0, k0, v0);
        EDGE_BODY(e1, k1, v1);
        EDGE_BODY(e2, k2, v2);
        EDGE_BODY(e3, k3, v3);
    }
    for (; j < jEnd; ++j) {
        int e = edgeIdx[s + j];
        int c = cols[e];
        ushort4 ku = ((const ushort4*)(Kb + (size_t)c * LATENT))[t];
        float4  vu = ((const float4*)(Vf + (size_t)c * LATENT))[t];
        EDGE_BODY(e, ku, vu);
    }
#undef EDGE_BODY

    // combine halves
    norm  += __shfl_xor(norm, 32);
    acc.x += __shfl_xor(acc.x, 32);
    acc.y += __shfl_xor(acc.y, 32);
    acc.z += __shfl_xor(acc.z, 32);
    acc.w += __shfl_xor(acc.w, 32);

    float rn = 1.f / (norm + 1e-8f);
    if (half == 0) {
        acc.x *= rn; acc.y *= rn; acc.z *= rn; acc.w *= rn;
        ((float4*)(outEmb + (size_t)node * LATENT))[t] = acc;
        if ((t & 3) == 0) rnArr[node * HEAD + h] = rn;
    }
}

// ---------------------------------------------------------------------------
// Kernel 3: normalize att in place: att[e,h] = expAtt[e,h] * rn[rows[e],h]
// ---------------------------------------------------------------------------
__global__ __launch_bounds__(256) void normalize_att(
    const int* __restrict__ rows, const float* __restrict__ rnArr,
    float* __restrict__ att, int nEdges)
{
    int tIdx = blockIdx.x * 256 + threadIdx.x;
    int e = tIdx >> 3;
    int h = tIdx & 7;
    if (e >= nEdges) return;
    int r = rows[e];
    att[e * HEAD + h] *= rnArr[r * HEAD + h];
}

// ---------------------------------------------------------------------------
extern "C" void kernel_launch(void* const* d_in, const int* in_sizes, int n_in,
                              void* d_out, int out_size, void* d_ws, size_t ws_size,
                              hipStream_t stream)
{
    const float* emb  = (const float*)d_in[0];
    const int*   rows = (const int*)d_in[1];
    const int*   cols = (const int*)d_in[2];
    const float* Wq   = (const float*)d_in[3];
    const float* Wk   = (const float*)d_in[4];
    const float* Wv   = (const float*)d_in[5];

    const int N = in_sizes[0] / LATENT;   // 50000
    const int E = in_sizes[1];            // 800000

    float* outEmb = (float*)d_out;                         // [N,128]
    float* attOut = (float*)d_out + (size_t)N * LATENT;    // [E,8]

    float* Qf = (float*)d_ws;                              // [N,128] fp32
    float* Vf = Qf + (size_t)N * LATENT;                   // [N,128] fp32
    unsigned short* Kb   = (unsigned short*)(Vf + (size_t)N * LATENT); // [N,128] bf16
    unsigned short* ehi  = Kb + (size_t)N * LATENT;        // [N,128] bf16
    unsigned short* elo  = ehi + (size_t)N * LATENT;       // [N,128] bf16
    unsigned short* Wthi = elo + (size_t)N * LATENT;       // [3,128,128] bf16
    unsigned short* Wtlo = Wthi + 3 * LATENT * LATENT;
    float* rnArr = (float*)(Wtlo + 3 * LATENT * LATENT);   // [N,8]
    int* deg       = (int*)(rnArr + (size_t)N * HEAD);
    int* excl      = deg + N;
    int* startArr  = excl + N;
    int* cursor    = startArr + N;
    int* blockSums = cursor + N;          // up to 64
    int* edgeIdx   = blockSums + 64;      // [E]

    hipMemsetAsync(deg, 0, (size_t)N * sizeof(int), stream);

    // 0. conversions / splits
    int n4 = N * LATENT / 4;
    convert_emb_hl<<<(n4 + 255) / 256, 256, 0, stream>>>(emb, ehi, elo, n4);
    convert_wt<<<(3 * LATENT * LATENT + 255) / 256, 256, 0, stream>>>(
        Wq, Wk, Wv, Wthi, Wtlo);

    // 1. QKV projections (split-bf16 MFMA; Q,K 3-term, V 1-term)
    dim3 gGemm((N + 127) / 128, 3);
    qkv_gemm_mfma<<<gGemm, 256, 0, stream>>>(ehi, elo, Wthi, Wtlo, Qf, Kb, Vf, N);

    // 2. CSR build
    count_deg<<<(E + 255) / 256, 256, 0, stream>>>(rows, deg, E);
    int nb = (N + SCAN_BLOCK - 1) / SCAN_BLOCK;
    scan_block<<<nb, SCAN_THREADS, 0, stream>>>(deg, excl, blockSums, N);
    scan_top<<<1, 64, 0, stream>>>(blockSums, nb);
    scan_add<<<(N + 255) / 256, 256, 0, stream>>>(excl, blockSums, startArr, cursor, N);
    scatter_edges<<<(E + 255) / 256, 256, 0, stream>>>(rows, cursor, edgeIdx, E);

    // 3. fused scores + aggregate (1 wave per node, split halves)
    node_fused<<<(N + 3) / 4, 256, 0, stream>>>(Qf, Kb, Vf, cols, startArr, deg,
                                                edgeIdx, attOut, rnArr, outEmb, N);

    // 4. normalize att in place
    int tScores = E * HEAD;
    normalize_att<<<(tScores + 255) / 256, 256, 0, stream>>>(rows, rnArr, attOut, E);
}

// Round 8
// 259.451 us; speedup vs baseline: 1.1407x; 1.1407x over previous
//
#include <hip/hip_runtime.h>

#define LATENT 128
#define HEAD 8
#define DH 16

#define SCAN_BLOCK 2048    // elements scanned per block
#define SCAN_THREADS 256   // 8 elements per thread

typedef __attribute__((ext_vector_type(8))) short short8;
typedef __attribute__((ext_vector_type(4))) float floatx4;

__device__ inline float bf2f(unsigned short u) {
    return __uint_as_float(((unsigned int)u) << 16);
}
__device__ inline unsigned short f2bf(float f) {
    unsigned int b = __float_as_uint(f);
    b += 0x7fffu + ((b >> 16) & 1u);          // RNE
    return (unsigned short)(b >> 16);
}

// ---------------------------------------------------------------------------
// emb -> bf16 hi/lo split (precomputed so GEMM staging is pure copies)
// ---------------------------------------------------------------------------
__global__ __launch_bounds__(256) void convert_emb_hl(
    const float* __restrict__ in, unsigned short* __restrict__ hi,
    unsigned short* __restrict__ lo, int n4)
{
    int i = blockIdx.x * 256 + threadIdx.x;
    if (i >= n4) return;
    float4 v = ((const float4*)in)[i];
    ushort4 h, l;
    h.x = f2bf(v.x); l.x = f2bf(v.x - bf2f(h.x));
    h.y = f2bf(v.y); l.y = f2bf(v.y - bf2f(h.y));
    h.z = f2bf(v.z); l.z = f2bf(v.z - bf2f(h.z));
    h.w = f2bf(v.w); l.w = f2bf(v.w - bf2f(h.w));
    ((ushort4*)hi)[i] = h;
    ((ushort4*)lo)[i] = l;
}

// ---------------------------------------------------------------------------
// Split W into bf16 hi/lo, transposed: Wt{hi,lo}[mat][c][k] from W[mat][k][c]
// ---------------------------------------------------------------------------
__global__ __launch_bounds__(256) void convert_wt(
    const float* __restrict__ Wq, const float* __restrict__ Wk, const float* __restrict__ Wv,
    unsigned short* __restrict__ Wthi, unsigned short* __restrict__ Wtlo)
{
    int idx = blockIdx.x * 256 + threadIdx.x;
    if (idx >= 3 * LATENT * LATENT) return;
    int mat = idx >> 14;
    int r   = idx & 16383;
    int c   = r >> 7;
    int k   = r & 127;
    const float* W = (mat == 0) ? Wq : ((mat == 1) ? Wk : Wv);
    float x = W[k * LATENT + c];
    unsigned short hi = f2bf(x);
    Wthi[idx] = hi;
    Wtlo[idx] = f2bf(x - bf2f(hi));
}

// ---------------------------------------------------------------------------
// Kernel 1: QKV projection via split-bf16 MFMA.
// Q,K: 3-term (fp32-accurate); V: 1-term (bf16-accurate, linear in output).
// Q -> fp32 array. K,V -> packed KV[node]: 32 chunks of {k4 bf16 | v4 bf16}
// (16 B per chunk) so node_fused does ONE uint4 gather per edge per lane.
// ---------------------------------------------------------------------------
__global__ __launch_bounds__(256) void qkv_gemm_mfma(
    const unsigned short* __restrict__ ehi, const unsigned short* __restrict__ elo,
    const unsigned short* __restrict__ Wthi, const unsigned short* __restrict__ Wtlo,
    float* __restrict__ Qf, unsigned short* __restrict__ KVb, int nNodes)
{
    __shared__ unsigned short sAhi[128 * 128];
    __shared__ unsigned short sAlo[128 * 128];
    __shared__ unsigned short sBhi[128 * 128];
    __shared__ unsigned short sBlo[128 * 128];   // 4 x 32 KB = 128 KB

    const int mat  = blockIdx.y;
    const int row0 = blockIdx.x * 128;
    const int tid  = threadIdx.x;
    const unsigned short* wthi = Wthi + mat * LATENT * LATENT;
    const unsigned short* wtlo = Wtlo + mat * LATENT * LATENT;

    // stage A (pre-split emb): 2048 16B-chunks each
#pragma unroll
    for (int it = 0; it < 8; ++it) {
        int g = it * 256 + tid;
        int r = g >> 4, c16 = g & 15;
        int gr = row0 + r;
        uint4 vh = make_uint4(0u, 0u, 0u, 0u);
        uint4 vl = make_uint4(0u, 0u, 0u, 0u);
        if (gr < nNodes) {
            vh = ((const uint4*)(ehi + (size_t)gr * LATENT))[c16];
            vl = ((const uint4*)(elo + (size_t)gr * LATENT))[c16];
        }
        int dst = r * 16 + (c16 ^ (r & 7));
        ((uint4*)sAhi)[dst] = vh;
        ((uint4*)sAlo)[dst] = vl;
    }
    // stage B: 2048 16B-chunks (lo only needed for Q,K)
#pragma unroll
    for (int it = 0; it < 8; ++it) {
        int g = it * 256 + tid;
        int r = g >> 4, c16 = g & 15;
        int dst = r * 16 + (c16 ^ (r & 7));
        ((uint4*)sBhi)[dst] = ((const uint4*)wthi)[g];
        if (mat < 2) ((uint4*)sBlo)[dst] = ((const uint4*)wtlo)[g];
    }
    __syncthreads();

    const int wid  = tid >> 6;
    const int lane = tid & 63;
    const int lrow = lane & 15;
    const int kgrp = lane >> 4;

    floatx4 acc[2][8];
#pragma unroll
    for (int rb = 0; rb < 2; ++rb)
#pragma unroll
        for (int cb = 0; cb < 8; ++cb)
            acc[rb][cb] = (floatx4){0.f, 0.f, 0.f, 0.f};

#pragma unroll
    for (int kk = 0; kk < 4; ++kk) {
        const int chunk = kk * 4 + kgrp;
        short8 ahi[2], alo[2], bhi[8], blo[8];
#pragma unroll
        for (int rb = 0; rb < 2; ++rb) {
            int rl  = wid * 32 + rb * 16 + lrow;
            int src = rl * 16 + (chunk ^ (rl & 7));
            ahi[rb] = ((const short8*)sAhi)[src];
            alo[rb] = ((const short8*)sAlo)[src];
        }
#pragma unroll
        for (int cb = 0; cb < 8; ++cb) {
            int cl  = cb * 16 + lrow;
            int src = cl * 16 + (chunk ^ (cl & 7));
            bhi[cb] = ((const short8*)sBhi)[src];
            blo[cb] = ((const short8*)sBlo)[src];
        }
        if (mat < 2) {
#pragma unroll
            for (int rb = 0; rb < 2; ++rb)
#pragma unroll
                for (int cb = 0; cb < 8; ++cb) {
                    acc[rb][cb] = __builtin_amdgcn_mfma_f32_16x16x32_bf16(
                        ahi[rb], bhi[cb], acc[rb][cb], 0, 0, 0);
                    acc[rb][cb] = __builtin_amdgcn_mfma_f32_16x16x32_bf16(
                        ahi[rb], blo[cb], acc[rb][cb], 0, 0, 0);
                    acc[rb][cb] = __builtin_amdgcn_mfma_f32_16x16x32_bf16(
                        alo[rb], bhi[cb], acc[rb][cb], 0, 0, 0);
                }
        } else {
#pragma unroll
            for (int rb = 0; rb < 2; ++rb)
#pragma unroll
                for (int cb = 0; cb < 8; ++cb)
                    acc[rb][cb] = __builtin_amdgcn_mfma_f32_16x16x32_bf16(
                        ahi[rb], bhi[cb], acc[rb][cb], 0, 0, 0);
        }
    }

    // C/D layout: col = lane&15, row = (lane>>4)*4 + reg   [m89-verified]
#pragma unroll
    for (int rb = 0; rb < 2; ++rb)
#pragma unroll
        for (int cb = 0; cb < 8; ++cb)
#pragma unroll
            for (int i = 0; i < 4; ++i) {
                int row = row0 + wid * 32 + rb * 16 + kgrp * 4 + i;
                int col = cb * 16 + lrow;
                if (row < nNodes) {
                    float v = acc[rb][cb][i];
                    if (mat == 0) {
                        Qf[(size_t)row * LATENT + col] = v;
                    } else {
                        // packed KV: chunk col>>2, slot col&3; K at +0, V at +4
                        size_t base = (size_t)row * 256 + ((col >> 2) << 3)
                                      + (col & 3) + (mat == 1 ? 0 : 4);
                        KVb[base] = f2bf(v);
                    }
                }
            }
}

// ---------------------------------------------------------------------------
// CSR build: histogram -> exclusive scan (3 kernels) -> scatter
// ---------------------------------------------------------------------------
__global__ __launch_bounds__(256) void count_deg(
    const int* __restrict__ rows, int* __restrict__ deg, int nE)
{
    int e = blockIdx.x * 256 + threadIdx.x;
    if (e < nE) atomicAdd(&deg[rows[e]], 1);
}

__global__ __launch_bounds__(SCAN_THREADS) void scan_block(
    const int* __restrict__ deg, int* __restrict__ excl,
    int* __restrict__ blockSums, int n)
{
    __shared__ int sSum[SCAN_THREADS];
    int tid  = threadIdx.x;
    int base = blockIdx.x * SCAN_BLOCK + tid * 8;
    int v[8];
    int tot = 0;
#pragma unroll
    for (int i = 0; i < 8; ++i) {
        int idx = base + i;
        v[i] = (idx < n) ? deg[idx] : 0;
        tot += v[i];
    }
    sSum[tid] = tot;
    __syncthreads();
    for (int off = 1; off < SCAN_THREADS; off <<= 1) {
        int x = (tid >= off) ? sSum[tid - off] : 0;
        __syncthreads();
        sSum[tid] += x;
        __syncthreads();
    }
    int run = (tid > 0) ? sSum[tid - 1] : 0;
#pragma unroll
    for (int i = 0; i < 8; ++i) {
        int idx = base + i;
        if (idx < n) excl[idx] = run;
        run += v[i];
    }
    if (tid == SCAN_THREADS - 1) blockSums[blockIdx.x] = sSum[SCAN_THREADS - 1];
}

__global__ void scan_top(int* __restrict__ blockSums, int nb)
{
    if (threadIdx.x == 0) {
        int run = 0;
        for (int i = 0; i < nb; ++i) {
            int x = blockSums[i];
            blockSums[i] = run;
            run += x;
        }
    }
}

__global__ __launch_bounds__(256) void scan_add(
    const int* __restrict__ excl, const int* __restrict__ blockSums,
    int* __restrict__ start, int* __restrict__ cursor, int n)
{
    int i = blockIdx.x * 256 + threadIdx.x;
    if (i < n) {
        int s = excl[i] + blockSums[i / SCAN_BLOCK];
        start[i]  = s;
        cursor[i] = s;
    }
}

// also writes colsSorted so the hot loop skips one indirection level
__global__ __launch_bounds__(256) void scatter_edges(
    const int* __restrict__ rows, const int* __restrict__ cols,
    int* __restrict__ cursor,
    int* __restrict__ edgeIdx, int* __restrict__ colsSorted, int nE)
{
    int e = blockIdx.x * 256 + threadIdx.x;
    if (e < nE) {
        int p = atomicAdd(&cursor[rows[e]], 1);
        edgeIdx[p]    = e;
        colsSorted[p] = cols[e];
    }
}

// ---------------------------------------------------------------------------
// Kernel 2: fused node-centric scores + aggregate.
// ONE 64-lane wave per node: lanes 0-31 edges [0,cnt/2), lanes 32-63 the rest.
// Lane t owns dims 4t..4t+3. Per edge: ONE uint4 gather of the packed
// {k4|v4} chunk; dot via 2x shfl_xor within the 4-lane head group; exp;
// accumulate sum(exp), sum(exp*v). Halves combined via shfl_xor(...,32).
// ---------------------------------------------------------------------------
__global__ __launch_bounds__(256) void node_fused(
    const float* __restrict__ Qf, const unsigned short* __restrict__ KVb,
    const int* __restrict__ start, const int* __restrict__ deg,
    const int* __restrict__ edgeIdx, const int* __restrict__ colsSorted,
    float* __restrict__ attOut,         // [E,8] <- exp (pre-normalization)
    float* __restrict__ rnArr,          // [N,8]
    float* __restrict__ outEmb, int nNodes)
{
    int node = blockIdx.x * 4 + (threadIdx.x >> 6);
    int lane = threadIdx.x & 63;
    int half = lane >> 5;
    int t    = lane & 31;               // lane owns dims 4t..4t+3
    if (node >= nNodes) return;
    int h = t >> 2;

    float4 q = ((const float4*)(Qf + (size_t)node * LATENT))[t];

    int s    = start[node];
    int cnt  = deg[node];
    int cnt2 = cnt >> 1;
    int jBeg = half ? cnt2 : 0;
    int jEnd = half ? cnt : cnt2;

    float4 acc = make_float4(0.f, 0.f, 0.f, 0.f);
    float norm = 0.f;

#define EDGE_BODY(E_, KV_)                                                     \
    {                                                                          \
        float p = q.x * bf2f((unsigned short)(KV_.x & 0xffff)) +               \
                  q.y * bf2f((unsigned short)(KV_.x >> 16)) +                  \
                  q.z * bf2f((unsigned short)(KV_.y & 0xffff)) +               \
                  q.w * bf2f((unsigned short)(KV_.y >> 16));                   \
        p += __shfl_xor(p, 1);                                                 \
        p += __shfl_xor(p, 2);                                                 \
        p = fminf(fmaxf(p, -10.f), 10.f);                                      \
        float ex = expf(p);                                                    \
        if ((t & 3) == 0) attOut[(size_t)E_ * HEAD + h] = ex;                  \
        norm += ex;                                                            \
        acc.x += ex * bf2f((unsigned short)(KV_.z & 0xffff));                  \
        acc.y += ex * bf2f((unsigned short)(KV_.z >> 16));                     \
        acc.z += ex * bf2f((unsigned short)(KV_.w & 0xffff));                  \
        acc.w += ex * bf2f((unsigned short)(KV_.w >> 16));                     \
    }

    int j = jBeg;
    for (; j + 4 <= jEnd; j += 4) {
        int c0 = colsSorted[s + j + 0];
        int c1 = colsSorted[s + j + 1];
        int c2 = colsSorted[s + j + 2];
        int c3 = colsSorted[s + j + 3];
        int e0 = edgeIdx[s + j + 0];
        int e1 = edgeIdx[s + j + 1];
        int e2 = edgeIdx[s + j + 2];
        int e3 = edgeIdx[s + j + 3];
        uint4 kv0 = ((const uint4*)(KVb + (size_t)c0 * 256))[t];
        uint4 kv1 = ((const uint4*)(KVb + (size_t)c1 * 256))[t];
        uint4 kv2 = ((const uint4*)(KVb + (size_t)c2 * 256))[t];
        uint4 kv3 = ((const uint4*)(KVb + (size_t)c3 * 256))[t];
        EDGE_BODY(e0, kv0);
        EDGE_BODY(e1, kv1);
        EDGE_BODY(e2, kv2);
        EDGE_BODY(e3, kv3);
    }
    for (; j < jEnd; ++j) {
        int c = colsSorted[s + j];
        int e = edgeIdx[s + j];
        uint4 kv = ((const uint4*)(KVb + (size_t)c * 256))[t];
        EDGE_BODY(e, kv);
    }
#undef EDGE_BODY

    // combine halves
    norm  += __shfl_xor(norm, 32);
    acc.x += __shfl_xor(acc.x, 32);
    acc.y += __shfl_xor(acc.y, 32);
    acc.z += __shfl_xor(acc.z, 32);
    acc.w += __shfl_xor(acc.w, 32);

    float rn = 1.f / (norm + 1e-8f);
    if (half == 0) {
        acc.x *= rn; acc.y *= rn; acc.z *= rn; acc.w *= rn;
        ((float4*)(outEmb + (size_t)node * LATENT))[t] = acc;
        if ((t & 3) == 0) rnArr[node * HEAD + h] = rn;
    }
}

// ---------------------------------------------------------------------------
// Kernel 3: normalize att in place: att[e,h] = expAtt[e,h] * rn[rows[e],h]
// ---------------------------------------------------------------------------
__global__ __launch_bounds__(256) void normalize_att(
    const int* __restrict__ rows, const float* __restrict__ rnArr,
    float* __restrict__ att, int nEdges)
{
    int tIdx = blockIdx.x * 256 + threadIdx.x;
    int e = tIdx >> 3;
    int h = tIdx & 7;
    if (e >= nEdges) return;
    int r = rows[e];
    att[e * HEAD + h] *= rnArr[r * HEAD + h];
}

// ---------------------------------------------------------------------------
extern "C" void kernel_launch(void* const* d_in, const int* in_sizes, int n_in,
                              void* d_out, int out_size, void* d_ws, size_t ws_size,
                              hipStream_t stream)
{
    const float* emb  = (const float*)d_in[0];
    const int*   rows = (const int*)d_in[1];
    const int*   cols = (const int*)d_in[2];
    const float* Wq   = (const float*)d_in[3];
    const float* Wk   = (const float*)d_in[4];
    const float* Wv   = (const float*)d_in[5];

    const int N = in_sizes[0] / LATENT;   // 50000
    const int E = in_sizes[1];            // 800000

    float* outEmb = (float*)d_out;                         // [N,128]
    float* attOut = (float*)d_out + (size_t)N * LATENT;    // [E,8]

    float* Qf = (float*)d_ws;                              // [N,128] fp32
    unsigned short* KVb  = (unsigned short*)(Qf + (size_t)N * LATENT); // [N,256] packed
    unsigned short* ehi  = KVb + (size_t)N * 256;          // [N,128] bf16
    unsigned short* elo  = ehi + (size_t)N * LATENT;       // [N,128] bf16
    unsigned short* Wthi = elo + (size_t)N * LATENT;       // [3,128,128] bf16
    unsigned short* Wtlo = Wthi + 3 * LATENT * LATENT;
    float* rnArr = (float*)(Wtlo + 3 * LATENT * LATENT);   // [N,8]
    int* deg        = (int*)(rnArr + (size_t)N * HEAD);
    int* excl       = deg + N;
    int* startArr   = excl + N;
    int* cursor     = startArr + N;
    int* blockSums  = cursor + N;          // up to 64
    int* edgeIdx    = blockSums + 64;      // [E]
    int* colsSorted = edgeIdx + E;         // [E]

    hipMemsetAsync(deg, 0, (size_t)N * sizeof(int), stream);

    // 0. conversions / splits
    int n4 = N * LATENT / 4;
    convert_emb_hl<<<(n4 + 255) / 256, 256, 0, stream>>>(emb, ehi, elo, n4);
    convert_wt<<<(3 * LATENT * LATENT + 255) / 256, 256, 0, stream>>>(
        Wq, Wk, Wv, Wthi, Wtlo);

    // 1. QKV projections (split-bf16 MFMA; Q,K 3-term, V 1-term)
    dim3 gGemm((N + 127) / 128, 3);
    qkv_gemm_mfma<<<gGemm, 256, 0, stream>>>(ehi, elo, Wthi, Wtlo, Qf, KVb, N);

    // 2. CSR build
    count_deg<<<(E + 255) / 256, 256, 0, stream>>>(rows, deg, E);
    int nb = (N + SCAN_BLOCK - 1) / SCAN_BLOCK;
    scan_block<<<nb, SCAN_THREADS, 0, stream>>>(deg, excl, blockSums, N);
    scan_top<<<1, 64, 0, stream>>>(blockSums, nb);
    scan_add<<<(N + 255) / 256, 256, 0, stream>>>(excl, blockSums, startArr, cursor, N);
    scatter_edges<<<(E + 255) / 256, 256, 0, stream>>>(rows, cols, cursor,
                                                       edgeIdx, colsSorted, E);

    // 3. fused scores + aggregate (1 wave per node, packed KV gather)
    node_fused<<<(N + 3) / 4, 256, 0, stream>>>(Qf, KVb, startArr, deg,
                                                edgeIdx, colsSorted,
                                                attOut, rnArr, outEmb, N);

    // 4. normalize att in place
    int tScores = E * HEAD;
    normalize_att<<<(tScores + 255) / 256, 256, 0, stream>>>(rows, rnArr, attOut, E);
}

// Round 9
// 233.072 us; speedup vs baseline: 1.2698x; 1.1132x over previous
//
#include <hip/hip_runtime.h>

#define LATENT 128
#define HEAD 8
#define DH 16

#define SCAN_BLOCK 2048    // elements scanned per block
#define SCAN_THREADS 256   // 8 elements per thread

typedef __attribute__((ext_vector_type(8))) short short8;
typedef __attribute__((ext_vector_type(4))) float floatx4;

__device__ inline float bf2f(unsigned short u) {
    return __uint_as_float(((unsigned int)u) << 16);
}
__device__ inline unsigned short f2bf(float f) {
    unsigned int b = __float_as_uint(f);
    b += 0x7fffu + ((b >> 16) & 1u);          // RNE
    return (unsigned short)(b >> 16);
}

// ---------------------------------------------------------------------------
// Split W into bf16 hi/lo, transposed: Wt{hi,lo}[mat][c][k] from W[mat][k][c]
// ---------------------------------------------------------------------------
__global__ __launch_bounds__(256) void convert_wt(
    const float* __restrict__ Wq, const float* __restrict__ Wk, const float* __restrict__ Wv,
    unsigned short* __restrict__ Wthi, unsigned short* __restrict__ Wtlo)
{
    int idx = blockIdx.x * 256 + threadIdx.x;
    if (idx >= 3 * LATENT * LATENT) return;
    int mat = idx >> 14;
    int r   = idx & 16383;
    int c   = r >> 7;
    int k   = r & 127;
    const float* W = (mat == 0) ? Wq : ((mat == 1) ? Wk : Wv);
    float x = W[k * LATENT + c];
    unsigned short hi = f2bf(x);
    Wthi[idx] = hi;
    Wtlo[idx] = f2bf(x - bf2f(hi));
}

// ---------------------------------------------------------------------------
// Kernel 1: QKV projection, A-in-registers split-bf16 MFMA.
// One block per 128-row tile; loops mat=0(Q),1(K),2(V) staging only B in LDS
// (64 KB -> 2 blocks/CU; all 391 blocks co-resident).
// Per lane: A fragments read directly from fp32 emb (16 rows x 4 chunks,
// 32 B each), split hi/lo in-register ONCE, reused for all 3 mats.
// Q,K: 3-term (fp32-accurate). V: 2-term (alo free in regs).
// Output: Q fp32; K,V packed bf16 KV[node] = 32 x {k4|v4} 16B chunks.
// ---------------------------------------------------------------------------
__global__ __launch_bounds__(256) void qkv_gemm_reg(
    const float* __restrict__ emb,
    const unsigned short* __restrict__ Wthi, const unsigned short* __restrict__ Wtlo,
    float* __restrict__ Qf, unsigned short* __restrict__ KVb, int nNodes)
{
    __shared__ unsigned short sBhi[128 * 128];   // 32 KB
    __shared__ unsigned short sBlo[128 * 128];   // 32 KB

    const int row0 = blockIdx.x * 128;
    const int tid  = threadIdx.x;
    const int wid  = tid >> 6;
    const int lane = tid & 63;
    const int lrow = lane & 15;
    const int kgrp = lane >> 4;

    // ---- A fragments: load fp32, split hi/lo in-register (once) ----
    short8 ahi[2][4], alo[2][4];
#pragma unroll
    for (int rb = 0; rb < 2; ++rb) {
        int row = row0 + wid * 32 + rb * 16 + lrow;
        if (row >= nNodes) row = nNodes - 1;      // clamped; writes are guarded
        const float* src = emb + (size_t)row * LATENT;
#pragma unroll
        for (int kk = 0; kk < 4; ++kk) {
            int chunk = kk * 4 + kgrp;
            float4 f0 = ((const float4*)(src + chunk * 8))[0];
            float4 f1 = ((const float4*)(src + chunk * 8))[1];
            float x[8] = {f0.x, f0.y, f0.z, f0.w, f1.x, f1.y, f1.z, f1.w};
            short8 h8, l8;
#pragma unroll
            for (int j = 0; j < 8; ++j) {
                unsigned short h = f2bf(x[j]);
                h8[j] = (short)h;
                l8[j] = (short)f2bf(x[j] - bf2f(h));
            }
            ahi[rb][kk] = h8;
            alo[rb][kk] = l8;
        }
    }

    for (int mat = 0; mat < 3; ++mat) {
        const unsigned short* wthi = Wthi + mat * LATENT * LATENT;
        const unsigned short* wtlo = Wtlo + mat * LATENT * LATENT;

        __syncthreads();   // prior mat's B reads complete before overwrite
#pragma unroll
        for (int it = 0; it < 8; ++it) {
            int g = it * 256 + tid;
            int r = g >> 4, c16 = g & 15;
            int dst = r * 16 + (c16 ^ (r & 7));
            ((uint4*)sBhi)[dst] = ((const uint4*)wthi)[g];
            if (mat < 2) ((uint4*)sBlo)[dst] = ((const uint4*)wtlo)[g];
        }
        __syncthreads();

        floatx4 acc[2][8];
#pragma unroll
        for (int rb = 0; rb < 2; ++rb)
#pragma unroll
            for (int cb = 0; cb < 8; ++cb)
                acc[rb][cb] = (floatx4){0.f, 0.f, 0.f, 0.f};

#pragma unroll
        for (int kk = 0; kk < 4; ++kk) {
            const int chunk = kk * 4 + kgrp;
            short8 bhi[8], blo[8];
#pragma unroll
            for (int cb = 0; cb < 8; ++cb) {
                int cl  = cb * 16 + lrow;
                int src = cl * 16 + (chunk ^ (cl & 7));
                bhi[cb] = ((const short8*)sBhi)[src];
                if (mat < 2) blo[cb] = ((const short8*)sBlo)[src];
            }
#pragma unroll
            for (int rb = 0; rb < 2; ++rb)
#pragma unroll
                for (int cb = 0; cb < 8; ++cb) {
                    acc[rb][cb] = __builtin_amdgcn_mfma_f32_16x16x32_bf16(
                        ahi[rb][kk], bhi[cb], acc[rb][cb], 0, 0, 0);
                    acc[rb][cb] = __builtin_amdgcn_mfma_f32_16x16x32_bf16(
                        alo[rb][kk], bhi[cb], acc[rb][cb], 0, 0, 0);
                    if (mat < 2)
                        acc[rb][cb] = __builtin_amdgcn_mfma_f32_16x16x32_bf16(
                            ahi[rb][kk], blo[cb], acc[rb][cb], 0, 0, 0);
                }
        }

        // C/D layout: col = lane&15, row = (lane>>4)*4 + reg   [m89-verified]
#pragma unroll
        for (int rb = 0; rb < 2; ++rb)
#pragma unroll
            for (int cb = 0; cb < 8; ++cb)
#pragma unroll
                for (int i = 0; i < 4; ++i) {
                    int row = row0 + wid * 32 + rb * 16 + kgrp * 4 + i;
                    int col = cb * 16 + lrow;
                    if (row < nNodes) {
                        float v = acc[rb][cb][i];
                        if (mat == 0) {
                            Qf[(size_t)row * LATENT + col] = v;
                        } else {
                            size_t base = (size_t)row * 256 + ((col >> 2) << 3)
                                          + (col & 3) + (mat == 1 ? 0 : 4);
                            KVb[base] = f2bf(v);
                        }
                    }
                }
    }
}

// ---------------------------------------------------------------------------
// CSR build: histogram -> exclusive scan (3 kernels) -> scatter
// ---------------------------------------------------------------------------
__global__ __launch_bounds__(256) void count_deg(
    const int* __restrict__ rows, int* __restrict__ deg, int nE)
{
    int e = blockIdx.x * 256 + threadIdx.x;
    if (e < nE) atomicAdd(&deg[rows[e]], 1);
}

__global__ __launch_bounds__(SCAN_THREADS) void scan_block(
    const int* __restrict__ deg, int* __restrict__ excl,
    int* __restrict__ blockSums, int n)
{
    __shared__ int sSum[SCAN_THREADS];
    int tid  = threadIdx.x;
    int base = blockIdx.x * SCAN_BLOCK + tid * 8;
    int v[8];
    int tot = 0;
#pragma unroll
    for (int i = 0; i < 8; ++i) {
        int idx = base + i;
        v[i] = (idx < n) ? deg[idx] : 0;
        tot += v[i];
    }
    sSum[tid] = tot;
    __syncthreads();
    for (int off = 1; off < SCAN_THREADS; off <<= 1) {
        int x = (tid >= off) ? sSum[tid - off] : 0;
        __syncthreads();
        sSum[tid] += x;
        __syncthreads();
    }
    int run = (tid > 0) ? sSum[tid - 1] : 0;
#pragma unroll
    for (int i = 0; i < 8; ++i) {
        int idx = base + i;
        if (idx < n) excl[idx] = run;
        run += v[i];
    }
    if (tid == SCAN_THREADS - 1) blockSums[blockIdx.x] = sSum[SCAN_THREADS - 1];
}

__global__ void scan_top(int* __restrict__ blockSums, int nb)
{
    if (threadIdx.x == 0) {
        int run = 0;
        for (int i = 0; i < nb; ++i) {
            int x = blockSums[i];
            blockSums[i] = run;
            run += x;
        }
    }
}

__global__ __launch_bounds__(256) void scan_add(
    const int* __restrict__ excl, const int* __restrict__ blockSums,
    int* __restrict__ start, int* __restrict__ cursor, int n)
{
    int i = blockIdx.x * 256 + threadIdx.x;
    if (i < n) {
        int s = excl[i] + blockSums[i / SCAN_BLOCK];
        start[i]  = s;
        cursor[i] = s;
    }
}

// writes packed (col, edge) pairs so the hot loop does ONE 8B load per edge
__global__ __launch_bounds__(256) void scatter_edges(
    const int* __restrict__ rows, const int* __restrict__ cols,
    int* __restrict__ cursor, int2* __restrict__ ce, int nE)
{
    int e = blockIdx.x * 256 + threadIdx.x;
    if (e < nE) {
        int p = atomicAdd(&cursor[rows[e]], 1);
        ce[p] = make_int2(cols[e], e);
    }
}

// ---------------------------------------------------------------------------
// Kernel 2: fused node-centric scores + aggregate + att normalization.
// ONE 64-lane wave per node; halves split the edge list; lane t owns dims
// 4t..4t+3 (4 lanes/head). Per edge: one uint4 gather of packed {k4|v4};
// dot via 2x shfl_xor; __expf; accumulate. Pass 2 rescales attOut by rn
// in-place (L1-hot; vmcnt(0) orders same-address store->load).
// ---------------------------------------------------------------------------
__global__ __launch_bounds__(256) void node_fused(
    const float* __restrict__ Qf, const unsigned short* __restrict__ KVb,
    const int* __restrict__ start, const int* __restrict__ deg,
    const int2* __restrict__ ce,
    float* __restrict__ attOut,         // [E,8]: pass1 exp, pass2 normalized
    float* __restrict__ outEmb, int nNodes)
{
    int node = blockIdx.x * 4 + (threadIdx.x >> 6);
    int lane = threadIdx.x & 63;
    int half = lane >> 5;
    int t    = lane & 31;               // lane owns dims 4t..4t+3
    if (node >= nNodes) return;
    int h = t >> 2;

    float4 q = ((const float4*)(Qf + (size_t)node * LATENT))[t];

    int s    = start[node];
    int cnt  = deg[node];
    int cnt2 = cnt >> 1;
    int jBeg = half ? cnt2 : 0;
    int jEnd = half ? cnt : cnt2;

    float4 acc = make_float4(0.f, 0.f, 0.f, 0.f);
    float norm = 0.f;

#define EDGE_BODY(E_, KV_)                                                     \
    {                                                                          \
        float p = q.x * bf2f((unsigned short)(KV_.x & 0xffff)) +               \
                  q.y * bf2f((unsigned short)(KV_.x >> 16)) +                  \
                  q.z * bf2f((unsigned short)(KV_.y & 0xffff)) +               \
                  q.w * bf2f((unsigned short)(KV_.y >> 16));                   \
        p += __shfl_xor(p, 1);                                                 \
        p += __shfl_xor(p, 2);                                                 \
        p = fminf(fmaxf(p, -10.f), 10.f);                                      \
        float ex = __expf(p);                                                  \
        if ((t & 3) == 0) attOut[(size_t)E_ * HEAD + h] = ex;                  \
        norm += ex;                                                            \
        acc.x += ex * bf2f((unsigned short)(KV_.z & 0xffff));                  \
        acc.y += ex * bf2f((unsigned short)(KV_.z >> 16));                     \
        acc.z += ex * bf2f((unsigned short)(KV_.w & 0xffff));                  \
        acc.w += ex * bf2f((unsigned short)(KV_.w >> 16));                     \
    }

    int j = jBeg;
    for (; j + 4 <= jEnd; j += 4) {
        int2 p0 = ce[s + j + 0];
        int2 p1 = ce[s + j + 1];
        int2 p2 = ce[s + j + 2];
        int2 p3 = ce[s + j + 3];
        uint4 kv0 = ((const uint4*)(KVb + (size_t)p0.x * 256))[t];
        uint4 kv1 = ((const uint4*)(KVb + (size_t)p1.x * 256))[t];
        uint4 kv2 = ((const uint4*)(KVb + (size_t)p2.x * 256))[t];
        uint4 kv3 = ((const uint4*)(KVb + (size_t)p3.x * 256))[t];
        EDGE_BODY(p0.y, kv0);
        EDGE_BODY(p1.y, kv1);
        EDGE_BODY(p2.y, kv2);
        EDGE_BODY(p3.y, kv3);
    }
    for (; j < jEnd; ++j) {
        int2 pp = ce[s + j];
        uint4 kv = ((const uint4*)(KVb + (size_t)pp.x * 256))[t];
        EDGE_BODY(pp.y, kv);
    }
#undef EDGE_BODY

    // combine halves
    norm  += __shfl_xor(norm, 32);
    acc.x += __shfl_xor(acc.x, 32);
    acc.y += __shfl_xor(acc.y, 32);
    acc.z += __shfl_xor(acc.z, 32);
    acc.w += __shfl_xor(acc.w, 32);

    float rn = 1.f / (norm + 1e-8f);
    if (half == 0) {
        float4 o = acc;
        o.x *= rn; o.y *= rn; o.z *= rn; o.w *= rn;
        ((float4*)(outEmb + (size_t)node * LATENT))[t] = o;
    }

    // ---- pass 2: normalize attOut in place (4 edges x 8 heads per half) ----
    asm volatile("s_waitcnt vmcnt(0)" ::: "memory");   // order pass1 stores
    float rnH = __shfl(rn, (t & 7) << 2);              // rn for head t&7
    for (int jj = jBeg + (t >> 3); jj < jEnd; jj += 4) {
        int e = ce[s + jj].y;
        attOut[(size_t)e * HEAD + (t & 7)] *= rnH;
    }
}

// ---------------------------------------------------------------------------
extern "C" void kernel_launch(void* const* d_in, const int* in_sizes, int n_in,
                              void* d_out, int out_size, void* d_ws, size_t ws_size,
                              hipStream_t stream)
{
    const float* emb  = (const float*)d_in[0];
    const int*   rows = (const int*)d_in[1];
    const int*   cols = (const int*)d_in[2];
    const float* Wq   = (const float*)d_in[3];
    const float* Wk   = (const float*)d_in[4];
    const float* Wv   = (const float*)d_in[5];

    const int N = in_sizes[0] / LATENT;   // 50000
    const int E = in_sizes[1];            // 800000

    float* outEmb = (float*)d_out;                         // [N,128]
    float* attOut = (float*)d_out + (size_t)N * LATENT;    // [E,8]

    float* Qf = (float*)d_ws;                              // [N,128] fp32
    unsigned short* KVb  = (unsigned short*)(Qf + (size_t)N * LATENT); // [N,256] packed
    unsigned short* Wthi = KVb + (size_t)N * 256;          // [3,128,128] bf16
    unsigned short* Wtlo = Wthi + 3 * LATENT * LATENT;
    int* deg        = (int*)(Wtlo + 3 * LATENT * LATENT);
    int* excl       = deg + N;
    int* startArr   = excl + N;
    int* cursor     = startArr + N;
    int* blockSums  = cursor + N;          // up to 64
    int2* ce        = (int2*)(blockSums + 64);   // [E] packed (col, edge)

    hipMemsetAsync(deg, 0, (size_t)N * sizeof(int), stream);

    // 0. split/transpose W
    convert_wt<<<(3 * LATENT * LATENT + 255) / 256, 256, 0, stream>>>(
        Wq, Wk, Wv, Wthi, Wtlo);

    // 1. QKV projections (A-in-registers split-bf16 MFMA; Q,K 3-term, V 2-term)
    qkv_gemm_reg<<<(N + 127) / 128, 256, 0, stream>>>(emb, Wthi, Wtlo, Qf, KVb, N);

    // 2. CSR build
    count_deg<<<(E + 255) / 256, 256, 0, stream>>>(rows, deg, E);
    int nb = (N + SCAN_BLOCK - 1) / SCAN_BLOCK;
    scan_block<<<nb, SCAN_THREADS, 0, stream>>>(deg, excl, blockSums, N);
    scan_top<<<1, 64, 0, stream>>>(blockSums, nb);
    scan_add<<<(N + 255) / 256, 256, 0, stream>>>(excl, blockSums, startArr, cursor, N);
    scatter_edges<<<(E + 255) / 256, 256, 0, stream>>>(rows, cols, cursor, ce, E);

    // 3. fused scores + aggregate + att normalization
    node_fused<<<(N + 3) / 4, 256, 0, stream>>>(Qf, KVb, startArr, deg, ce,
                                                attOut, outEmb, N);
}

// Round 10
// 227.680 us; speedup vs baseline: 1.2998x; 1.0237x over previous
//
#include <hip/hip_runtime.h>

#define LATENT 128
#define HEAD 8
#define DH 16

#define SCAN_BLOCK 2048    // elements scanned per block
#define SCAN_THREADS 256   // 8 elements per thread

typedef __attribute__((ext_vector_type(8))) short short8;
typedef __attribute__((ext_vector_type(4))) float floatx4;

__device__ inline float bf2f(unsigned short u) {
    return __uint_as_float(((unsigned int)u) << 16);
}
__device__ inline unsigned short f2bf(float f) {
    unsigned int b = __float_as_uint(f);
    b += 0x7fffu + ((b >> 16) & 1u);          // RNE
    return (unsigned short)(b >> 16);
}

// ---------------------------------------------------------------------------
// Split W into bf16 hi/lo, transposed: Wt{hi,lo}[mat][c][k] from W[mat][k][c]
// ---------------------------------------------------------------------------
__global__ __launch_bounds__(256) void convert_wt(
    const float* __restrict__ Wq, const float* __restrict__ Wk, const float* __restrict__ Wv,
    unsigned short* __restrict__ Wthi, unsigned short* __restrict__ Wtlo)
{
    int idx = blockIdx.x * 256 + threadIdx.x;
    if (idx >= 3 * LATENT * LATENT) return;
    int mat = idx >> 14;
    int r   = idx & 16383;
    int c   = r >> 7;
    int k   = r & 127;
    const float* W = (mat == 0) ? Wq : ((mat == 1) ? Wk : Wv);
    float x = W[k * LATENT + c];
    unsigned short hi = f2bf(x);
    Wthi[idx] = hi;
    Wtlo[idx] = f2bf(x - bf2f(hi));
}

// ---------------------------------------------------------------------------
// Kernel 1: QKV projection, A-in-registers split-bf16 MFMA.
// One block per 128-row tile; loops mat=0(Q),1(K),2(V) staging only B in LDS
// (64 KB -> 2 blocks/CU). A fragments read from fp32 emb, split hi/lo once.
// Q,K: 3-term (fp32-accurate). V: 2-term. Output: Q fp32; K,V packed bf16.
// ---------------------------------------------------------------------------
__global__ __launch_bounds__(256) void qkv_gemm_reg(
    const float* __restrict__ emb,
    const unsigned short* __restrict__ Wthi, const unsigned short* __restrict__ Wtlo,
    float* __restrict__ Qf, unsigned short* __restrict__ KVb, int nNodes)
{
    __shared__ unsigned short sBhi[128 * 128];   // 32 KB
    __shared__ unsigned short sBlo[128 * 128];   // 32 KB

    const int row0 = blockIdx.x * 128;
    const int tid  = threadIdx.x;
    const int wid  = tid >> 6;
    const int lane = tid & 63;
    const int lrow = lane & 15;
    const int kgrp = lane >> 4;

    // ---- A fragments: load fp32, split hi/lo in-register (once) ----
    short8 ahi[2][4], alo[2][4];
#pragma unroll
    for (int rb = 0; rb < 2; ++rb) {
        int row = row0 + wid * 32 + rb * 16 + lrow;
        if (row >= nNodes) row = nNodes - 1;      // clamped; writes are guarded
        const float* src = emb + (size_t)row * LATENT;
#pragma unroll
        for (int kk = 0; kk < 4; ++kk) {
            int chunk = kk * 4 + kgrp;
            float4 f0 = ((const float4*)(src + chunk * 8))[0];
            float4 f1 = ((const float4*)(src + chunk * 8))[1];
            float x[8] = {f0.x, f0.y, f0.z, f0.w, f1.x, f1.y, f1.z, f1.w};
            short8 h8, l8;
#pragma unroll
            for (int j = 0; j < 8; ++j) {
                unsigned short h = f2bf(x[j]);
                h8[j] = (short)h;
                l8[j] = (short)f2bf(x[j] - bf2f(h));
            }
            ahi[rb][kk] = h8;
            alo[rb][kk] = l8;
        }
    }

    for (int mat = 0; mat < 3; ++mat) {
        const unsigned short* wthi = Wthi + mat * LATENT * LATENT;
        const unsigned short* wtlo = Wtlo + mat * LATENT * LATENT;

        __syncthreads();   // prior mat's B reads complete before overwrite
#pragma unroll
        for (int it = 0; it < 8; ++it) {
            int g = it * 256 + tid;
            int r = g >> 4, c16 = g & 15;
            int dst = r * 16 + (c16 ^ (r & 7));
            ((uint4*)sBhi)[dst] = ((const uint4*)wthi)[g];
            if (mat < 2) ((uint4*)sBlo)[dst] = ((const uint4*)wtlo)[g];
        }
        __syncthreads();

        floatx4 acc[2][8];
#pragma unroll
        for (int rb = 0; rb < 2; ++rb)
#pragma unroll
            for (int cb = 0; cb < 8; ++cb)
                acc[rb][cb] = (floatx4){0.f, 0.f, 0.f, 0.f};

#pragma unroll
        for (int kk = 0; kk < 4; ++kk) {
            const int chunk = kk * 4 + kgrp;
            short8 bhi[8], blo[8];
#pragma unroll
            for (int cb = 0; cb < 8; ++cb) {
                int cl  = cb * 16 + lrow;
                int src = cl * 16 + (chunk ^ (cl & 7));
                bhi[cb] = ((const short8*)sBhi)[src];
                if (mat < 2) blo[cb] = ((const short8*)sBlo)[src];
            }
#pragma unroll
            for (int rb = 0; rb < 2; ++rb)
#pragma unroll
                for (int cb = 0; cb < 8; ++cb) {
                    acc[rb][cb] = __builtin_amdgcn_mfma_f32_16x16x32_bf16(
                        ahi[rb][kk], bhi[cb], acc[rb][cb], 0, 0, 0);
                    acc[rb][cb] = __builtin_amdgcn_mfma_f32_16x16x32_bf16(
                        alo[rb][kk], bhi[cb], acc[rb][cb], 0, 0, 0);
                    if (mat < 2)
                        acc[rb][cb] = __builtin_amdgcn_mfma_f32_16x16x32_bf16(
                            ahi[rb][kk], blo[cb], acc[rb][cb], 0, 0, 0);
                }
        }

        // C/D layout: col = lane&15, row = (lane>>4)*4 + reg   [m89-verified]
#pragma unroll
        for (int rb = 0; rb < 2; ++rb)
#pragma unroll
            for (int cb = 0; cb < 8; ++cb)
#pragma unroll
                for (int i = 0; i < 4; ++i) {
                    int row = row0 + wid * 32 + rb * 16 + kgrp * 4 + i;
                    int col = cb * 16 + lrow;
                    if (row < nNodes) {
                        float v = acc[rb][cb][i];
                        if (mat == 0) {
                            Qf[(size_t)row * LATENT + col] = v;
                        } else {
                            size_t base = (size_t)row * 256 + ((col >> 2) << 3)
                                          + (col & 3) + (mat == 1 ? 0 : 4);
                            KVb[base] = f2bf(v);
                        }
                    }
                }
    }
}

// ---------------------------------------------------------------------------
// CSR build: histogram -> exclusive scan (3 kernels) -> scatter
// ---------------------------------------------------------------------------
__global__ __launch_bounds__(256) void count_deg(
    const int* __restrict__ rows, int* __restrict__ deg, int nE)
{
    int e = blockIdx.x * 256 + threadIdx.x;
    if (e < nE) atomicAdd(&deg[rows[e]], 1);
}

__global__ __launch_bounds__(SCAN_THREADS) void scan_block(
    const int* __restrict__ deg, int* __restrict__ excl,
    int* __restrict__ blockSums, int n)
{
    __shared__ int sSum[SCAN_THREADS];
    int tid  = threadIdx.x;
    int base = blockIdx.x * SCAN_BLOCK + tid * 8;
    int v[8];
    int tot = 0;
#pragma unroll
    for (int i = 0; i < 8; ++i) {
        int idx = base + i;
        v[i] = (idx < n) ? deg[idx] : 0;
        tot += v[i];
    }
    sSum[tid] = tot;
    __syncthreads();
    for (int off = 1; off < SCAN_THREADS; off <<= 1) {
        int x = (tid >= off) ? sSum[tid - off] : 0;
        __syncthreads();
        sSum[tid] += x;
        __syncthreads();
    }
    int run = (tid > 0) ? sSum[tid - 1] : 0;
#pragma unroll
    for (int i = 0; i < 8; ++i) {
        int idx = base + i;
        if (idx < n) excl[idx] = run;
        run += v[i];
    }
    if (tid == SCAN_THREADS - 1) blockSums[blockIdx.x] = sSum[SCAN_THREADS - 1];
}

__global__ void scan_top(int* __restrict__ blockSums, int nb)
{
    if (threadIdx.x == 0) {
        int run = 0;
        for (int i = 0; i < nb; ++i) {
            int x = blockSums[i];
            blockSums[i] = run;
            run += x;
        }
    }
}

__global__ __launch_bounds__(256) void scan_add(
    const int* __restrict__ excl, const int* __restrict__ blockSums,
    int* __restrict__ start, int* __restrict__ cursor, int n)
{
    int i = blockIdx.x * 256 + threadIdx.x;
    if (i < n) {
        int s = excl[i] + blockSums[i / SCAN_BLOCK];
        start[i]  = s;
        cursor[i] = s;
    }
}

// writes packed (col, edge) pairs so the hot loop does ONE 8B load per edge
__global__ __launch_bounds__(256) void scatter_edges(
    const int* __restrict__ rows, const int* __restrict__ cols,
    int* __restrict__ cursor, int2* __restrict__ ce, int nE)
{
    int e = blockIdx.x * 256 + threadIdx.x;
    if (e < nE) {
        int p = atomicAdd(&cursor[rows[e]], 1);
        ce[p] = make_int2(cols[e], e);
    }
}

// ---------------------------------------------------------------------------
// Kernel 2: fused node-centric scores + aggregate (pass 1 only).
// ONE 64-lane wave per node; halves split the edge list; lane t owns dims
// 4t..4t+3 (4 lanes/head). Per edge: one uint4 gather of packed {k4|v4};
// dot via 2x shfl_xor; __expf; accumulate. Writes rnArr for normalize_att.
// ---------------------------------------------------------------------------
__global__ __launch_bounds__(256) void node_fused(
    const float* __restrict__ Qf, const unsigned short* __restrict__ KVb,
    const int* __restrict__ start, const int* __restrict__ deg,
    const int2* __restrict__ ce,
    float* __restrict__ attOut,         // [E,8] <- exp (pre-normalization)
    float* __restrict__ rnArr,          // [N,8]
    float* __restrict__ outEmb, int nNodes)
{
    int node = blockIdx.x * 4 + (threadIdx.x >> 6);
    int lane = threadIdx.x & 63;
    int half = lane >> 5;
    int t    = lane & 31;               // lane owns dims 4t..4t+3
    if (node >= nNodes) return;
    int h = t >> 2;

    float4 q = ((const float4*)(Qf + (size_t)node * LATENT))[t];

    int s    = start[node];
    int cnt  = deg[node];
    int cnt2 = cnt >> 1;
    int jBeg = half ? cnt2 : 0;
    int jEnd = half ? cnt : cnt2;

    float4 acc = make_float4(0.f, 0.f, 0.f, 0.f);
    float norm = 0.f;

#define EDGE_BODY(E_, KV_)                                                     \
    {                                                                          \
        float p = q.x * bf2f((unsigned short)(KV_.x & 0xffff)) +               \
                  q.y * bf2f((unsigned short)(KV_.x >> 16)) +                  \
                  q.z * bf2f((unsigned short)(KV_.y & 0xffff)) +               \
                  q.w * bf2f((unsigned short)(KV_.y >> 16));                   \
        p += __shfl_xor(p, 1);                                                 \
        p += __shfl_xor(p, 2);                                                 \
        p = fminf(fmaxf(p, -10.f), 10.f);                                      \
        float ex = __expf(p);                                                  \
        if ((t & 3) == 0) attOut[(size_t)E_ * HEAD + h] = ex;                  \
        norm += ex;                                                            \
        acc.x += ex * bf2f((unsigned short)(KV_.z & 0xffff));                  \
        acc.y += ex * bf2f((unsigned short)(KV_.z >> 16));                     \
        acc.z += ex * bf2f((unsigned short)(KV_.w & 0xffff));                  \
        acc.w += ex * bf2f((unsigned short)(KV_.w >> 16));                     \
    }

    int j = jBeg;
    for (; j + 4 <= jEnd; j += 4) {
        int2 p0 = ce[s + j + 0];
        int2 p1 = ce[s + j + 1];
        int2 p2 = ce[s + j + 2];
        int2 p3 = ce[s + j + 3];
        uint4 kv0 = ((const uint4*)(KVb + (size_t)p0.x * 256))[t];
        uint4 kv1 = ((const uint4*)(KVb + (size_t)p1.x * 256))[t];
        uint4 kv2 = ((const uint4*)(KVb + (size_t)p2.x * 256))[t];
        uint4 kv3 = ((const uint4*)(KVb + (size_t)p3.x * 256))[t];
        EDGE_BODY(p0.y, kv0);
        EDGE_BODY(p1.y, kv1);
        EDGE_BODY(p2.y, kv2);
        EDGE_BODY(p3.y, kv3);
    }
    for (; j < jEnd; ++j) {
        int2 pp = ce[s + j];
        uint4 kv = ((const uint4*)(KVb + (size_t)pp.x * 256))[t];
        EDGE_BODY(pp.y, kv);
    }
#undef EDGE_BODY

    // combine halves
    norm  += __shfl_xor(norm, 32);
    acc.x += __shfl_xor(acc.x, 32);
    acc.y += __shfl_xor(acc.y, 32);
    acc.z += __shfl_xor(acc.z, 32);
    acc.w += __shfl_xor(acc.w, 32);

    float rn = 1.f / (norm + 1e-8f);
    if (half == 0) {
        acc.x *= rn; acc.y *= rn; acc.z *= rn; acc.w *= rn;
        ((float4*)(outEmb + (size_t)node * LATENT))[t] = acc;
        if ((t & 3) == 0) rnArr[node * HEAD + h] = rn;
    }
}

// ---------------------------------------------------------------------------
// Kernel 3: normalize att in place: att[e,h] = expAtt[e,h] * rn[rows[e],h]
// Streaming coalesced RMW; overlaps freely across blocks.
// ---------------------------------------------------------------------------
__global__ __launch_bounds__(256) void normalize_att(
    const int* __restrict__ rows, const float* __restrict__ rnArr,
    float* __restrict__ att, int nEdges)
{
    int tIdx = blockIdx.x * 256 + threadIdx.x;
    int e = tIdx >> 3;
    int h = tIdx & 7;
    if (e >= nEdges) return;
    int r = rows[e];
    att[e * HEAD + h] *= rnArr[r * HEAD + h];
}

// ---------------------------------------------------------------------------
extern "C" void kernel_launch(void* const* d_in, const int* in_sizes, int n_in,
                              void* d_out, int out_size, void* d_ws, size_t ws_size,
                              hipStream_t stream)
{
    const float* emb  = (const float*)d_in[0];
    const int*   rows = (const int*)d_in[1];
    const int*   cols = (const int*)d_in[2];
    const float* Wq   = (const float*)d_in[3];
    const float* Wk   = (const float*)d_in[4];
    const float* Wv   = (const float*)d_in[5];

    const int N = in_sizes[0] / LATENT;   // 50000
    const int E = in_sizes[1];            // 800000

    float* outEmb = (float*)d_out;                         // [N,128]
    float* attOut = (float*)d_out + (size_t)N * LATENT;    // [E,8]

    float* Qf = (float*)d_ws;                              // [N,128] fp32
    unsigned short* KVb  = (unsigned short*)(Qf + (size_t)N * LATENT); // [N,256] packed
    unsigned short* Wthi = KVb + (size_t)N * 256;          // [3,128,128] bf16
    unsigned short* Wtlo = Wthi + 3 * LATENT * LATENT;
    float* rnArr   = (float*)(Wtlo + 3 * LATENT * LATENT); // [N,8]
    int* deg        = (int*)(rnArr + (size_t)N * HEAD);
    int* excl       = deg + N;
    int* startArr   = excl + N;
    int* cursor     = startArr + N;
    int* blockSums  = cursor + N;          // up to 64
    int2* ce        = (int2*)(blockSums + 64);   // [E] packed (col, edge)

    hipMemsetAsync(deg, 0, (size_t)N * sizeof(int), stream);

    // 0. split/transpose W
    convert_wt<<<(3 * LATENT * LATENT + 255) / 256, 256, 0, stream>>>(
        Wq, Wk, Wv, Wthi, Wtlo);

    // 1. QKV projections (A-in-registers split-bf16 MFMA; Q,K 3-term, V 2-term)
    qkv_gemm_reg<<<(N + 127) / 128, 256, 0, stream>>>(emb, Wthi, Wtlo, Qf, KVb, N);

    // 2. CSR build
    count_deg<<<(E + 255) / 256, 256, 0, stream>>>(rows, deg, E);
    int nb = (N + SCAN_BLOCK - 1) / SCAN_BLOCK;
    scan_block<<<nb, SCAN_THREADS, 0, stream>>>(deg, excl, blockSums, N);
    scan_top<<<1, 64, 0, stream>>>(blockSums, nb);
    scan_add<<<(N + 255) / 256, 256, 0, stream>>>(excl, blockSums, startArr, cursor, N);
    scatter_edges<<<(E + 255) / 256, 256, 0, stream>>>(rows, cols, cursor, ce, E);

    // 3. fused scores + aggregate
    node_fused<<<(N + 3) / 4, 256, 0, stream>>>(Qf, KVb, startArr, deg, ce,
                                                attOut, rnArr, outEmb, N);

    // 4. normalize att in place (streaming)
    int tScores = E * HEAD;
    normalize_att<<<(tScores + 255) / 256, 256, 0, stream>>>(rows, rnArr, attOut, E);
}